// Round 1
// baseline (2366.219 us; speedup 1.0000x reference)
//
#include <hip/hip_runtime.h>

#define NN 100000
#define EE 500000
#define FIN 64
#define HH 128
#define BN_EPS 1e-5f

// ---------------- degree / norm precompute ----------------

__global__ __launch_bounds__(256) void deg_kernel(const int* __restrict__ dst,
                                                  float* __restrict__ deg) {
    int e = blockIdx.x * 256 + threadIdx.x;
    if (e < EE) unsafeAtomicAdd(&deg[dst[e]], 1.0f);
}

__global__ __launch_bounds__(256) void dinv_kernel(float* __restrict__ deg) {
    int i = blockIdx.x * 256 + threadIdx.x;
    if (i < NN) deg[i] = rsqrtf(deg[i] + 1.0f);
}

__global__ __launch_bounds__(256) void norm_kernel(const int* __restrict__ src,
                                                   const int* __restrict__ dst,
                                                   const float* __restrict__ dinv,
                                                   float* __restrict__ norm) {
    int e = blockIdx.x * 256 + threadIdx.x;
    if (e < EE) norm[e] = dinv[src[e]] * dinv[dst[e]];
}

// ---------------- aggregation: agg = diag(dinv^2) x  +  scatter(x[src]*norm -> dst)

template<int F>
__global__ __launch_bounds__(256) void init_scaled(const float* __restrict__ x,
                                                   const float* __restrict__ dinv,
                                                   float* __restrict__ agg) {
    constexpr int F4 = F / 4;
    int tid = blockIdx.x * 256 + threadIdx.x;
    int r = tid / F4;
    int f = (tid % F4) * 4;
    if (r >= NN) return;
    float sn = dinv[r];
    sn *= sn;
    float4 xv = *(const float4*)&x[(size_t)r * F + f];
    float4 o;
    o.x = xv.x * sn; o.y = xv.y * sn; o.z = xv.z * sn; o.w = xv.w * sn;
    *(float4*)&agg[(size_t)r * F + f] = o;
}

template<int F>
__global__ __launch_bounds__(256) void scatter_kernel(const float* __restrict__ x,
                                                      const int* __restrict__ src,
                                                      const int* __restrict__ dst,
                                                      const float* __restrict__ norm,
                                                      float* __restrict__ agg) {
    constexpr int F4 = F / 4;
    int tid = blockIdx.x * 256 + threadIdx.x;
    int e = tid / F4;
    int f = (tid % F4) * 4;
    if (e >= EE) return;
    int s = src[e];
    int d = dst[e];
    float nm = norm[e];
    float4 xv = *(const float4*)&x[(size_t)s * F + f];
    float* ap = &agg[(size_t)d * F + f];
    unsafeAtomicAdd(ap + 0, xv.x * nm);
    unsafeAtomicAdd(ap + 1, xv.y * nm);
    unsafeAtomicAdd(ap + 2, xv.z * nm);
    unsafeAtomicAdd(ap + 3, xv.w * nm);
}

// ---------------- fused GEMM + bias + BN(eval) + ReLU (+ residual) ----------------
// out[N][128] = relu( (A[N][K] @ W[K][128] + b - m) * g * rsqrt(v+eps) + be ) (+ res)

template<int K>
__global__ __launch_bounds__(256) void gemm_bn_relu(const float* __restrict__ A,
                                                    const float* __restrict__ W,
                                                    const float* __restrict__ bias,
                                                    const float* __restrict__ g,
                                                    const float* __restrict__ be,
                                                    const float* __restrict__ m,
                                                    const float* __restrict__ v,
                                                    const float* __restrict__ res,
                                                    float* __restrict__ out) {
    __shared__ float Wl[K * HH];
    int tid = threadIdx.x;
    for (int i = tid * 4; i < K * HH; i += 1024)
        *(float4*)&Wl[i] = *(const float4*)&W[i];
    __syncthreads();

    int tx = tid & 15;       // 16 col groups of 8 cols
    int ty = tid >> 4;       // 16 row groups of 4 rows
    int cbase = tx * 8;
    int r0 = blockIdx.x * 64 + ty * 4;
    if (r0 >= NN) return;    // after the only barrier
    int nr = NN - r0; if (nr > 4) nr = 4;

    int rid[4];
    #pragma unroll
    for (int rr = 0; rr < 4; rr++) rid[rr] = r0 + ((rr < nr) ? rr : 0);

    float acc[4][8];
    #pragma unroll
    for (int rr = 0; rr < 4; rr++)
        #pragma unroll
        for (int cc = 0; cc < 8; cc++) acc[rr][cc] = 0.0f;

    for (int k = 0; k < K; k += 4) {
        float a[4][4];
        #pragma unroll
        for (int rr = 0; rr < 4; rr++) {
            float4 t = *(const float4*)&A[(size_t)rid[rr] * K + k];
            a[rr][0] = t.x; a[rr][1] = t.y; a[rr][2] = t.z; a[rr][3] = t.w;
        }
        #pragma unroll
        for (int kk = 0; kk < 4; kk++) {
            float4 w0 = *(const float4*)&Wl[(k + kk) * HH + cbase];
            float4 w1 = *(const float4*)&Wl[(k + kk) * HH + cbase + 4];
            float wv[8] = {w0.x, w0.y, w0.z, w0.w, w1.x, w1.y, w1.z, w1.w};
            #pragma unroll
            for (int rr = 0; rr < 4; rr++)
                #pragma unroll
                for (int cc = 0; cc < 8; cc++)
                    acc[rr][cc] += a[rr][kk] * wv[cc];
        }
    }

    // epilogue: bias + BN + relu (+ residual)
    float sc[8], sh[8];
    #pragma unroll
    for (int cc = 0; cc < 8; cc++) {
        int c = cbase + cc;
        float s = g[c] * rsqrtf(v[c] + BN_EPS);
        sc[cc] = s;
        sh[cc] = (bias[c] - m[c]) * s + be[c];
    }
    for (int rr = 0; rr < nr; rr++) {
        int r = r0 + rr;
        float o[8];
        #pragma unroll
        for (int cc = 0; cc < 8; cc++) {
            float val = acc[rr][cc] * sc[cc] + sh[cc];
            val = fmaxf(val, 0.0f);
            if (res) val += res[(size_t)r * HH + cbase + cc];
            o[cc] = val;
        }
        *(float4*)&out[(size_t)r * HH + cbase]     = make_float4(o[0], o[1], o[2], o[3]);
        *(float4*)&out[(size_t)r * HH + cbase + 4] = make_float4(o[4], o[5], o[6], o[7]);
    }
}

// ---------------- layer 4: z = x3 @ W4 (128 -> 1), wave per row ----------------

__global__ __launch_bounds__(256) void gemv_kernel(const float* __restrict__ x3,
                                                   const float* __restrict__ W4,
                                                   float* __restrict__ z) {
    int gtid = blockIdx.x * 256 + threadIdx.x;
    int row = gtid >> 6;
    int lane = gtid & 63;
    if (row >= NN) return;
    float2 xv = *(const float2*)&x3[(size_t)row * HH + lane * 2];
    float2 wv = *(const float2*)&W4[lane * 2];
    float s = xv.x * wv.x + xv.y * wv.y;
    #pragma unroll
    for (int off = 32; off; off >>= 1) s += __shfl_xor(s, off, 64);
    if (lane == 0) z[row] = s;
}

__global__ __launch_bounds__(256) void final_init(const float* __restrict__ z,
                                                  const float* __restrict__ dinv,
                                                  const float* __restrict__ b4,
                                                  float* __restrict__ out) {
    int i = blockIdx.x * 256 + threadIdx.x;
    if (i < NN) out[i] = z[i] * dinv[i] * dinv[i] + b4[0];
}

__global__ __launch_bounds__(256) void final_scatter(const float* __restrict__ z,
                                                     const int* __restrict__ src,
                                                     const int* __restrict__ dst,
                                                     const float* __restrict__ norm,
                                                     float* __restrict__ out) {
    int e = blockIdx.x * 256 + threadIdx.x;
    if (e < EE) unsafeAtomicAdd(&out[dst[e]], z[src[e]] * norm[e]);
}

// ---------------- launch ----------------

extern "C" void kernel_launch(void* const* d_in, const int* in_sizes, int n_in,
                              void* d_out, int out_size, void* d_ws, size_t ws_size,
                              hipStream_t stream) {
    const float* x   = (const float*)d_in[0];
    const int*   ei  = (const int*)d_in[1];
    const int*   src = ei;
    const int*   dst = ei + EE;
    const float* W1 = (const float*)d_in[2];
    const float* b1 = (const float*)d_in[3];
    const float* g1 = (const float*)d_in[4];
    const float* be1 = (const float*)d_in[5];
    const float* m1 = (const float*)d_in[6];
    const float* v1 = (const float*)d_in[7];
    const float* W2 = (const float*)d_in[8];
    const float* b2 = (const float*)d_in[9];
    const float* g2 = (const float*)d_in[10];
    const float* be2 = (const float*)d_in[11];
    const float* m2 = (const float*)d_in[12];
    const float* v2 = (const float*)d_in[13];
    const float* W3 = (const float*)d_in[14];
    const float* b3 = (const float*)d_in[15];
    const float* g3 = (const float*)d_in[16];
    const float* be3 = (const float*)d_in[17];
    const float* m3 = (const float*)d_in[18];
    const float* v3 = (const float*)d_in[19];
    const float* W4 = (const float*)d_in[20];
    const float* b4 = (const float*)d_in[21];

    float* w    = (float*)d_ws;
    float* dinv = w;                                // N
    float* norm = dinv + NN;                        // E
    float* z    = norm + EE;                        // N
    float* x1   = z + NN;                           // N*H
    float* bufA = x1 + (size_t)NN * HH;             // N*H
    float* bufB = bufA + (size_t)NN * HH;           // N*H

    float* outp = (float*)d_out;

    hipMemsetAsync(dinv, 0, NN * sizeof(float), stream);
    deg_kernel<<<(EE + 255) / 256, 256, 0, stream>>>(dst, dinv);
    dinv_kernel<<<(NN + 255) / 256, 256, 0, stream>>>(dinv);
    norm_kernel<<<(EE + 255) / 256, 256, 0, stream>>>(src, dst, dinv, norm);

    // ---- layer 1: aggregate x (64 feat), then GEMM 64->128 + BN + ReLU
    init_scaled<FIN><<<(NN * (FIN / 4) + 255) / 256, 256, 0, stream>>>(x, dinv, bufA);
    scatter_kernel<FIN><<<(EE * (FIN / 4) + 255) / 256, 256, 0, stream>>>(x, src, dst, norm, bufA);
    gemm_bn_relu<FIN><<<(NN + 63) / 64, 256, 0, stream>>>(bufA, W1, b1, g1, be1, m1, v1, nullptr, x1);

    // ---- layer 2
    init_scaled<HH><<<(NN * (HH / 4) + 255) / 256, 256, 0, stream>>>(x1, dinv, bufA);
    scatter_kernel<HH><<<(EE * (HH / 4) + 255) / 256, 256, 0, stream>>>(x1, src, dst, norm, bufA);
    gemm_bn_relu<HH><<<(NN + 63) / 64, 256, 0, stream>>>(bufA, W2, b2, g2, be2, m2, v2, nullptr, bufB);

    // ---- layer 3 (+ residual x1 after relu)
    init_scaled<HH><<<(NN * (HH / 4) + 255) / 256, 256, 0, stream>>>(bufB, dinv, bufA);
    scatter_kernel<HH><<<(EE * (HH / 4) + 255) / 256, 256, 0, stream>>>(bufB, src, dst, norm, bufA);
    gemm_bn_relu<HH><<<(NN + 63) / 64, 256, 0, stream>>>(bufA, W3, b3, g3, be3, m3, v3, x1, bufB);

    // ---- layer 4: GEMV first (128->1), then aggregate scalars
    gemv_kernel<<<(NN + 3) / 4, 256, 0, stream>>>(bufB, W4, z);
    final_init<<<(NN + 255) / 256, 256, 0, stream>>>(z, dinv, b4, outp);
    final_scatter<<<(EE + 255) / 256, 256, 0, stream>>>(z, src, dst, norm, outp);
}

// Round 2
// 444.957 us; speedup vs baseline: 5.3179x; 5.3179x over previous
//
#include <hip/hip_runtime.h>

#define NN 100000
#define EE 500000
#define FIN 64
#define HH 128
#define BN_EPS 1e-5f
#define NB ((NN + 255) / 256)   // 391 scan blocks

// ---------------- CSR build ----------------

__global__ __launch_bounds__(256) void hist_kernel(const int* __restrict__ dst,
                                                   int* __restrict__ deg) {
    int e = blockIdx.x * 256 + threadIdx.x;
    if (e < EE) atomicAdd(&deg[dst[e]], 1);
}

__global__ __launch_bounds__(256) void dinv_kernel(const int* __restrict__ deg,
                                                   float* __restrict__ dinv) {
    int i = blockIdx.x * 256 + threadIdx.x;
    if (i < NN) dinv[i] = rsqrtf((float)deg[i] + 1.0f);
}

// per-block exclusive scan of deg -> rowstart, block totals -> blksum
__global__ __launch_bounds__(256) void scan1_kernel(const int* __restrict__ deg,
                                                    int* __restrict__ rowstart,
                                                    int* __restrict__ blksum) {
    __shared__ int s[256];
    int t = threadIdx.x;
    int i = blockIdx.x * 256 + t;
    int v = (i < NN) ? deg[i] : 0;
    s[t] = v;
    __syncthreads();
    #pragma unroll
    for (int off = 1; off < 256; off <<= 1) {
        int add = (t >= off) ? s[t - off] : 0;
        __syncthreads();
        s[t] += add;
        __syncthreads();
    }
    if (i < NN) rowstart[i] = s[t] - v;
    if (t == 255) blksum[blockIdx.x] = s[255];
}

// single-block exclusive scan of blksum[NB] in place
__global__ __launch_bounds__(512) void scan2_kernel(int* __restrict__ blksum) {
    __shared__ int s[512];
    int t = threadIdx.x;
    int v = (t < NB) ? blksum[t] : 0;
    s[t] = v;
    __syncthreads();
    #pragma unroll
    for (int off = 1; off < 512; off <<= 1) {
        int add = (t >= off) ? s[t - off] : 0;
        __syncthreads();
        s[t] += add;
        __syncthreads();
    }
    if (t < NB) blksum[t] = s[t] - v;
}

__global__ __launch_bounds__(256) void scan3_kernel(int* __restrict__ rowstart,
                                                    const int* __restrict__ blksum,
                                                    int* __restrict__ cursor) {
    int i = blockIdx.x * 256 + threadIdx.x;
    if (i < NN) {
        int r = rowstart[i] + blksum[i >> 8];
        rowstart[i] = r;
        cursor[i] = r;
    }
    if (i == 0) rowstart[NN] = EE;
}

// scatter edges into CSR slots: csr[pos] = (src, bitcast(norm))
__global__ __launch_bounds__(256) void fill_kernel(const int* __restrict__ src,
                                                   const int* __restrict__ dst,
                                                   const float* __restrict__ dinv,
                                                   int* __restrict__ cursor,
                                                   int2* __restrict__ csr) {
    int e = blockIdx.x * 256 + threadIdx.x;
    if (e >= EE) return;
    int s = src[e];
    int d = dst[e];
    float nm = dinv[s] * dinv[d];
    int pos = atomicAdd(&cursor[d], 1);
    csr[pos] = make_int2(s, __float_as_int(nm));
}

// ---------------- gather aggregation ----------------
// out[i] = x[i]*dinv[i]^2 + sum_{e in row i} x[csr[e].src] * w[e]

// 128 feats: one wave per node, float2 per lane
__global__ __launch_bounds__(256) void agg128_kernel(const float* __restrict__ x,
                                                     const int2* __restrict__ csr,
                                                     const int* __restrict__ rowstart,
                                                     const float* __restrict__ dinv,
                                                     float* __restrict__ out) {
    int gid = blockIdx.x * 4 + (threadIdx.x >> 6);
    int lane = threadIdx.x & 63;
    if (gid >= NN) return;
    float sn = dinv[gid];
    sn *= sn;
    float2 acc = *(const float2*)&x[(size_t)gid * HH + lane * 2];
    acc.x *= sn; acc.y *= sn;
    int e0 = rowstart[gid], e1 = rowstart[gid + 1];
    for (int e = e0; e < e1; e++) {
        int2 ed = csr[e];
        float w = __int_as_float(ed.y);
        float2 xs = *(const float2*)&x[(size_t)ed.x * HH + lane * 2];
        acc.x += xs.x * w;
        acc.y += xs.y * w;
    }
    *(float2*)&out[(size_t)gid * HH + lane * 2] = acc;
}

// 64 feats: half-wave (32 lanes) per node, float2 per lane
__global__ __launch_bounds__(256) void agg64_kernel(const float* __restrict__ x,
                                                    const int2* __restrict__ csr,
                                                    const int* __restrict__ rowstart,
                                                    const float* __restrict__ dinv,
                                                    float* __restrict__ out) {
    int gid = blockIdx.x * 8 + (threadIdx.x >> 5);
    int lane = threadIdx.x & 31;
    if (gid >= NN) return;
    float sn = dinv[gid];
    sn *= sn;
    float2 acc = *(const float2*)&x[(size_t)gid * FIN + lane * 2];
    acc.x *= sn; acc.y *= sn;
    int e0 = rowstart[gid], e1 = rowstart[gid + 1];
    for (int e = e0; e < e1; e++) {
        int2 ed = csr[e];
        float w = __int_as_float(ed.y);
        float2 xs = *(const float2*)&x[(size_t)ed.x * FIN + lane * 2];
        acc.x += xs.x * w;
        acc.y += xs.y * w;
    }
    *(float2*)&out[(size_t)gid * FIN + lane * 2] = acc;
}

// ---------------- fused GEMM + bias + BN(eval) + ReLU (+ residual) ----------------

template<int K>
__global__ __launch_bounds__(256) void gemm_bn_relu(const float* __restrict__ A,
                                                    const float* __restrict__ W,
                                                    const float* __restrict__ bias,
                                                    const float* __restrict__ g,
                                                    const float* __restrict__ be,
                                                    const float* __restrict__ m,
                                                    const float* __restrict__ v,
                                                    const float* __restrict__ res,
                                                    float* __restrict__ out) {
    __shared__ float Wl[K * HH];
    int tid = threadIdx.x;
    for (int i = tid * 4; i < K * HH; i += 1024)
        *(float4*)&Wl[i] = *(const float4*)&W[i];
    __syncthreads();

    int tx = tid & 15;       // 16 col groups of 8 cols
    int ty = tid >> 4;       // 16 row groups of 4 rows
    int cbase = tx * 8;
    int r0 = blockIdx.x * 64 + ty * 4;
    if (r0 >= NN) return;    // after the only barrier
    int nr = NN - r0; if (nr > 4) nr = 4;

    int rid[4];
    #pragma unroll
    for (int rr = 0; rr < 4; rr++) rid[rr] = r0 + ((rr < nr) ? rr : 0);

    float acc[4][8];
    #pragma unroll
    for (int rr = 0; rr < 4; rr++)
        #pragma unroll
        for (int cc = 0; cc < 8; cc++) acc[rr][cc] = 0.0f;

    for (int k = 0; k < K; k += 4) {
        float a[4][4];
        #pragma unroll
        for (int rr = 0; rr < 4; rr++) {
            float4 t = *(const float4*)&A[(size_t)rid[rr] * K + k];
            a[rr][0] = t.x; a[rr][1] = t.y; a[rr][2] = t.z; a[rr][3] = t.w;
        }
        #pragma unroll
        for (int kk = 0; kk < 4; kk++) {
            float4 w0 = *(const float4*)&Wl[(k + kk) * HH + cbase];
            float4 w1 = *(const float4*)&Wl[(k + kk) * HH + cbase + 4];
            float wv[8] = {w0.x, w0.y, w0.z, w0.w, w1.x, w1.y, w1.z, w1.w};
            #pragma unroll
            for (int rr = 0; rr < 4; rr++)
                #pragma unroll
                for (int cc = 0; cc < 8; cc++)
                    acc[rr][cc] += a[rr][kk] * wv[cc];
        }
    }

    float sc[8], sh[8];
    #pragma unroll
    for (int cc = 0; cc < 8; cc++) {
        int c = cbase + cc;
        float s = g[c] * rsqrtf(v[c] + BN_EPS);
        sc[cc] = s;
        sh[cc] = (bias[c] - m[c]) * s + be[c];
    }
    for (int rr = 0; rr < nr; rr++) {
        int r = r0 + rr;
        float o[8];
        #pragma unroll
        for (int cc = 0; cc < 8; cc++) {
            float val = acc[rr][cc] * sc[cc] + sh[cc];
            val = fmaxf(val, 0.0f);
            if (res) val += res[(size_t)r * HH + cbase + cc];
            o[cc] = val;
        }
        *(float4*)&out[(size_t)r * HH + cbase]     = make_float4(o[0], o[1], o[2], o[3]);
        *(float4*)&out[(size_t)r * HH + cbase + 4] = make_float4(o[4], o[5], o[6], o[7]);
    }
}

// ---------------- layer 4: z = x3 @ W4 (128 -> 1), wave per row ----------------

__global__ __launch_bounds__(256) void gemv_kernel(const float* __restrict__ x3,
                                                   const float* __restrict__ W4,
                                                   float* __restrict__ z) {
    int gtid = blockIdx.x * 256 + threadIdx.x;
    int row = gtid >> 6;
    int lane = gtid & 63;
    if (row >= NN) return;
    float2 xv = *(const float2*)&x3[(size_t)row * HH + lane * 2];
    float2 wv = *(const float2*)&W4[lane * 2];
    float s = xv.x * wv.x + xv.y * wv.y;
    #pragma unroll
    for (int off = 32; off; off >>= 1) s += __shfl_xor(s, off, 64);
    if (lane == 0) z[row] = s;
}

// final: out[i] = b4 + z[i]*dinv^2 + sum z[src]*w   (thread per node, CSR gather)
__global__ __launch_bounds__(256) void final_kernel(const float* __restrict__ z,
                                                    const int2* __restrict__ csr,
                                                    const int* __restrict__ rowstart,
                                                    const float* __restrict__ dinv,
                                                    const float* __restrict__ b4,
                                                    float* __restrict__ out) {
    int i = blockIdx.x * 256 + threadIdx.x;
    if (i >= NN) return;
    float acc = z[i] * dinv[i] * dinv[i] + b4[0];
    int e0 = rowstart[i], e1 = rowstart[i + 1];
    for (int e = e0; e < e1; e++) {
        int2 ed = csr[e];
        acc += z[ed.x] * __int_as_float(ed.y);
    }
    out[i] = acc;
}

// ---------------- launch ----------------

extern "C" void kernel_launch(void* const* d_in, const int* in_sizes, int n_in,
                              void* d_out, int out_size, void* d_ws, size_t ws_size,
                              hipStream_t stream) {
    const float* x   = (const float*)d_in[0];
    const int*   ei  = (const int*)d_in[1];
    const int*   src = ei;
    const int*   dst = ei + EE;
    const float* W1 = (const float*)d_in[2];
    const float* b1 = (const float*)d_in[3];
    const float* g1 = (const float*)d_in[4];
    const float* be1 = (const float*)d_in[5];
    const float* m1 = (const float*)d_in[6];
    const float* v1 = (const float*)d_in[7];
    const float* W2 = (const float*)d_in[8];
    const float* b2 = (const float*)d_in[9];
    const float* g2 = (const float*)d_in[10];
    const float* be2 = (const float*)d_in[11];
    const float* m2 = (const float*)d_in[12];
    const float* v2 = (const float*)d_in[13];
    const float* W3 = (const float*)d_in[14];
    const float* b3 = (const float*)d_in[15];
    const float* g3 = (const float*)d_in[16];
    const float* be3 = (const float*)d_in[17];
    const float* m3 = (const float*)d_in[18];
    const float* v3 = (const float*)d_in[19];
    const float* W4 = (const float*)d_in[20];
    const float* b4 = (const float*)d_in[21];

    char* wp = (char*)d_ws;
    int*   deg      = (int*)wp;                      wp += (size_t)NN * 4;
    int*   blksum   = (int*)wp;                      wp += 512 * 4;
    int*   rowstart = (int*)wp;                      wp += (size_t)(NN + 1) * 4;
    int*   cursor   = (int*)wp;                      wp += (size_t)NN * 4;
    float* dinv     = (float*)wp;                    wp += (size_t)NN * 4;
    int2*  csr      = (int2*)wp;                     wp += (size_t)EE * 8;
    float* z        = (float*)wp;                    wp += (size_t)NN * 4;
    float* x1       = (float*)wp;                    wp += (size_t)NN * HH * 4;
    float* bufA     = (float*)wp;                    wp += (size_t)NN * HH * 4;
    float* bufB     = (float*)wp;                    wp += (size_t)NN * HH * 4;

    float* outp = (float*)d_out;

    // ---- CSR build
    hipMemsetAsync(deg, 0, (size_t)NN * 4, stream);
    hist_kernel<<<(EE + 255) / 256, 256, 0, stream>>>(dst, deg);
    dinv_kernel<<<(NN + 255) / 256, 256, 0, stream>>>(deg, dinv);
    scan1_kernel<<<NB, 256, 0, stream>>>(deg, rowstart, blksum);
    scan2_kernel<<<1, 512, 0, stream>>>(blksum);
    scan3_kernel<<<NB, 256, 0, stream>>>(rowstart, blksum, cursor);
    fill_kernel<<<(EE + 255) / 256, 256, 0, stream>>>(src, dst, dinv, cursor, csr);

    // ---- layer 1: aggregate x (64 feat), then GEMM 64->128 + BN + ReLU
    agg64_kernel<<<(NN + 7) / 8, 256, 0, stream>>>(x, csr, rowstart, dinv, bufA);
    gemm_bn_relu<FIN><<<(NN + 63) / 64, 256, 0, stream>>>(bufA, W1, b1, g1, be1, m1, v1, nullptr, x1);

    // ---- layer 2
    agg128_kernel<<<(NN + 3) / 4, 256, 0, stream>>>(x1, csr, rowstart, dinv, bufA);
    gemm_bn_relu<HH><<<(NN + 63) / 64, 256, 0, stream>>>(bufA, W2, b2, g2, be2, m2, v2, nullptr, bufB);

    // ---- layer 3 (+ residual x1 after relu)
    agg128_kernel<<<(NN + 3) / 4, 256, 0, stream>>>(bufB, csr, rowstart, dinv, bufA);
    gemm_bn_relu<HH><<<(NN + 63) / 64, 256, 0, stream>>>(bufA, W3, b3, g3, be3, m3, v3, x1, bufB);

    // ---- layer 4: GEMV first (128->1), then gather-aggregate scalars
    gemv_kernel<<<(NN + 3) / 4, 256, 0, stream>>>(bufB, W4, z);
    final_kernel<<<(NN + 255) / 256, 256, 0, stream>>>(z, csr, rowstart, dinv, b4, outp);
}